// Round 1
// baseline (1508.269 us; speedup 1.0000x reference)
//
#include <hip/hip_runtime.h>

// Problem constants (fixed by reference)
#define NN   20000
#define RR   11
#define BB   8
#define IND  300
#define OUTD 256
#define EE   640000
#define RN   (RR * NN)      // 220000 buckets, key = rel*N + src
#define KP   304            // K padded to 19 * 16 for 32x32x16 MFMA
#define SBS  308            // LDS bf16 row stride: 616B -> 2-way bank aliasing (free)
#define NSCAN_BLOCKS 215    // ceil(220000 / 1024)

typedef short bf16x8 __attribute__((ext_vector_type(8)));
typedef float f32x16 __attribute__((ext_vector_type(16)));

union U8 {
    bf16x8  v;
    ushort4 h[2];
    uint4   q;
};

__device__ inline unsigned short f2bf(float f) {
    union { float f; unsigned u; } x;
    x.f = f;
    unsigned u = x.u;
    u += 0x7fffu + ((u >> 16) & 1u);   // round-to-nearest-even
    return (unsigned short)(u >> 16);
}

// ---------------------------------------------------------------- zero hist
__global__ __launch_bounds__(256) void k_zero(unsigned* __restrict__ hist) {
    const unsigned i = blockIdx.x * 256u + threadIdx.x;
    if (i < RN) hist[i] = 0u;
}

// ------------------------------------------- Wt[r][o][k] bf16, K zero-padded
__global__ __launch_bounds__(256) void k_wt(const float* __restrict__ comps,
                                            const float* __restrict__ bases,
                                            unsigned short* __restrict__ wt) {
    const unsigned idx = blockIdx.x * 256u + threadIdx.x;   // exactly 856064
    const unsigned r   = idx / (OUTD * KP);
    const unsigned rem = idx - r * (OUTD * KP);
    const unsigned o   = rem / KP;
    const unsigned k   = rem - o * KP;
    float acc = 0.f;
    if (k < IND) {
#pragma unroll
        for (int b = 0; b < BB; ++b)
            acc += comps[r * BB + b] * bases[((unsigned)b * IND + k) * OUTD + o];
    }
    wt[idx] = f2bf(acc);
}

// ---------------------------------------------------------------- histogram
__global__ __launch_bounds__(256) void k_hist(const int* __restrict__ esrc,
                                              const int* __restrict__ erel,
                                              unsigned* __restrict__ hist) {
    const int e = blockIdx.x * 256 + threadIdx.x;           // exactly 640000
    const unsigned key = (unsigned)erel[e] * NN + (unsigned)esrc[e];
    atomicAdd(&hist[key], 1u);
}

// ------------------------------------------------- scan level 1 (1024/block)
__global__ __launch_bounds__(256) void k_scan1(const unsigned* __restrict__ hist,
                                               unsigned* __restrict__ off,
                                               unsigned* __restrict__ bsum) {
    __shared__ unsigned sc[256];
    const int tid = threadIdx.x;
    const unsigned base = blockIdx.x * 1024u + (unsigned)tid * 4u;
    unsigned v0 = (base + 0 < RN) ? hist[base + 0] : 0u;
    unsigned v1 = (base + 1 < RN) ? hist[base + 1] : 0u;
    unsigned v2 = (base + 2 < RN) ? hist[base + 2] : 0u;
    unsigned v3 = (base + 3 < RN) ? hist[base + 3] : 0u;
    const unsigned s = v0 + v1 + v2 + v3;
    sc[tid] = s;
    __syncthreads();
    for (int d = 1; d < 256; d <<= 1) {
        unsigned t = (tid >= d) ? sc[tid - d] : 0u;
        __syncthreads();
        sc[tid] += t;
        __syncthreads();
    }
    if (tid == 255) bsum[blockIdx.x] = sc[255];
    unsigned run = sc[tid] - s;                              // exclusive
    if (base + 0 < RN) off[base + 0] = run; run += v0;
    if (base + 1 < RN) off[base + 1] = run; run += v1;
    if (base + 2 < RN) off[base + 2] = run; run += v2;
    if (base + 3 < RN) off[base + 3] = run;
}

// --------------------------------------------- scan level 2 (215 block sums)
__global__ void k_scan2(unsigned* __restrict__ bsum) {
    unsigned run = 0;
    for (int i = 0; i < NSCAN_BLOCKS; ++i) {
        unsigned t = bsum[i];
        bsum[i] = run;
        run += t;
    }
}

// ------------------------------------------------ scan level 3 (+cursor copy)
__global__ __launch_bounds__(256) void k_scan3(unsigned* __restrict__ off,
                                               unsigned* __restrict__ off2,
                                               const unsigned* __restrict__ bsum) {
    const unsigned idx = blockIdx.x * 256u + threadIdx.x;
    if (idx < RN) {
        const unsigned v = off[idx] + bsum[idx >> 10];
        off[idx]  = v;
        off2[idx] = v;
    }
    if (idx == 0) off[RN] = EE;
}

// ------------------------------------------------------- counting-sort scatter
__global__ __launch_bounds__(256) void k_scatter(const int* __restrict__ esrc,
                                                 const int* __restrict__ erel,
                                                 const int* __restrict__ edst,
                                                 unsigned* __restrict__ off2,
                                                 unsigned* __restrict__ ssd) {
    const int e = blockIdx.x * 256 + threadIdx.x;           // exactly 640000
    const unsigned src = (unsigned)esrc[e];
    const unsigned key = (unsigned)erel[e] * NN + src;
    const unsigned p = atomicAdd(&off2[key], 1u);
    ssd[p] = (src << 16) | (unsigned)edst[e];
}

// ---------------------------------------------------------------- fused main
// 32 nodes/block, 512 threads (8 waves). Per relation: edge-parallel gather
// into fp32 LDS, scale+convert to bf16, 19 MFMA k-steps into persistent acc.
__global__ __launch_bounds__(512) void k_main(const float* __restrict__ feat,
                                              const float* __restrict__ bias,
                                              const unsigned* __restrict__ offs,
                                              const unsigned* __restrict__ ssd,
                                              const unsigned short* __restrict__ wt,
                                              float* __restrict__ out) {
    __shared__ float s32[32 * IND];
    __shared__ __align__(16) unsigned short sbf[32 * SBS];

    const int tid  = threadIdx.x;
    const int wave = tid >> 6;
    const int lane = tid & 63;
    const int row  = lane & 31;      // MFMA: A row / B col / C col
    const int q    = lane >> 5;
    const int n0   = blockIdx.x * 32;
    const int o0   = wave * 32;      // each wave owns a 32-wide output stripe

    f32x16 acc;
#pragma unroll
    for (int i = 0; i < 16; ++i) acc[i] = 0.f;

    for (int r = 0; r < RR; ++r) {
        // --- zero fp32 accumulation tile
        for (int i = tid; i < 32 * IND; i += 512) s32[i] = 0.f;
        __syncthreads();

        // --- edge-parallel gather (LDS fp32 atomics; lanes -> consecutive banks)
        const unsigned e0 = offs[r * NN + n0];
        const unsigned e1 = offs[r * NN + n0 + 32];
        for (unsigned e = e0 + (unsigned)wave; e < e1; e += 8) {
            const unsigned sd = ssd[e];
            const int m       = (int)(sd >> 16) - n0;
            const unsigned d  = sd & 0xFFFFu;
            const float* fp   = feat + (size_t)d * IND + lane;
            const float v0 = fp[0];
            const float v1 = fp[64];
            const float v2 = fp[128];
            const float v3 = fp[192];
            const float v4 = (lane < IND - 256) ? fp[256] : 0.f;
            float* sp = s32 + m * IND + lane;
            atomicAdd(sp,       v0);
            atomicAdd(sp + 64,  v1);
            atomicAdd(sp + 128, v2);
            atomicAdd(sp + 192, v3);
            if (lane < IND - 256) atomicAdd(sp + 256, v4);
        }
        __syncthreads();

        // --- scale by 1/deg and convert to bf16 (zero-pad K to 304, pad to 308)
        {
            const int m  = tid >> 4;
            const int k0 = tid & 15;
            const unsigned c0 = offs[r * NN + n0 + m];
            const unsigned c1 = offs[r * NN + n0 + m + 1];
            const float inv = (c1 > c0) ? 1.0f / (float)(c1 - c0) : 0.f;
            for (int k = k0; k < SBS; k += 16) {
                const float v = (k < IND) ? s32[m * IND + k] * inv : 0.f;
                sbf[m * SBS + k] = f2bf(v);
            }
        }
        __syncthreads();

        // --- MFMA: C[32 nodes x 32 outs] += A[32 x 304] * B[304 x 32]
        const unsigned short* wb = wt + ((size_t)(r * OUTD + o0 + row) * KP) + 8 * q;
        const unsigned short* ab = sbf + row * SBS + 8 * q;
#pragma unroll
        for (int ks = 0; ks < 19; ++ks) {
            const int kk = ks * 16;
            U8 a, b;
            a.h[0] = *(const ushort4*)(ab + kk);
            a.h[1] = *(const ushort4*)(ab + kk + 4);
            b.q    = *(const uint4*)(wb + kk);
            acc = __builtin_amdgcn_mfma_f32_32x32x16_bf16(a.v, b.v, acc, 0, 0, 0);
        }
        // no barrier needed: next writes to sbf are behind two barriers
    }

    // --- epilogue: C/D layout col=lane&31, row=(reg&3)+8*(reg>>2)+4*(lane>>5)
    const int o = o0 + row;
    const float bv = bias[o];
#pragma unroll
    for (int reg = 0; reg < 16; ++reg) {
        const int node = (reg & 3) + 8 * (reg >> 2) + 4 * q;
        out[(size_t)(n0 + node) * OUTD + o] = acc[reg] + bv;
    }
}

extern "C" void kernel_launch(void* const* d_in, const int* in_sizes, int n_in,
                              void* d_out, int out_size, void* d_ws, size_t ws_size,
                              hipStream_t stream) {
    const float* feat  = (const float*)d_in[0];
    const float* comps = (const float*)d_in[1];
    const float* bases = (const float*)d_in[2];
    const float* bias  = (const float*)d_in[3];
    const int*   esrc  = (const int*)d_in[4];
    const int*   erel  = (const int*)d_in[5];
    const int*   edst  = (const int*)d_in[6];
    float* out = (float*)d_out;

    char* ws = (char*)d_ws;
    // ws layout (bytes):
    unsigned short* wt   = (unsigned short*)(ws + 0);        // 11*256*304*2 = 1,712,128
    unsigned*       hist = (unsigned*)(ws + 1712128);        // 220000 u32
    unsigned*       off  = (unsigned*)(ws + 2592128);        // 220001 u32
    unsigned*       off2 = (unsigned*)(ws + 3472144);        // 220000 u32
    unsigned*       bsum = (unsigned*)(ws + 4352144);        // 215 u32
    unsigned*       ssd  = (unsigned*)(ws + 4353008);        // 640000 u32 -> 6,913,008 total

    hipLaunchKernelGGL(k_zero,    dim3(860),  dim3(256), 0, stream, hist);
    hipLaunchKernelGGL(k_wt,      dim3(3344), dim3(256), 0, stream, comps, bases, wt);
    hipLaunchKernelGGL(k_hist,    dim3(2500), dim3(256), 0, stream, esrc, erel, hist);
    hipLaunchKernelGGL(k_scan1,   dim3(NSCAN_BLOCKS), dim3(256), 0, stream, hist, off, bsum);
    hipLaunchKernelGGL(k_scan2,   dim3(1),    dim3(1),   0, stream, bsum);
    hipLaunchKernelGGL(k_scan3,   dim3(860),  dim3(256), 0, stream, off, off2, bsum);
    hipLaunchKernelGGL(k_scatter, dim3(2500), dim3(256), 0, stream, esrc, erel, edst, off2, ssd);
    hipLaunchKernelGGL(k_main,    dim3(625),  dim3(512), 0, stream, feat, bias, off, ssd, wt, out);

    (void)in_sizes; (void)n_in; (void)out_size; (void)ws_size;
}

// Round 2
// 1505.214 us; speedup vs baseline: 1.0020x; 1.0020x over previous
//
#include <hip/hip_runtime.h>

// Problem constants (fixed by reference)
#define NN   20000
#define RR   11
#define BB   8
#define IND  300
#define OUTD 256
#define EE   640000
#define RN   (RR * NN)      // 220000 buckets, key = rel*N + src
#define KP   304            // K padded to 19 * 16 for 32x32x16 MFMA
#define SBS  308            // LDS bf16 row stride: 616B -> 2-way bank aliasing (free)
#define NSCAN_BLOCKS 215    // ceil(220000 / 1024)
#define CHUNK 512           // edges staged in LDS per gather chunk

typedef short bf16x8 __attribute__((ext_vector_type(8)));
typedef float f32x16 __attribute__((ext_vector_type(16)));

union U8 {
    bf16x8  v;
    ushort4 h[2];
    uint4   q;
};

__device__ inline unsigned short f2bf(float f) {
    union { float f; unsigned u; } x;
    x.f = f;
    unsigned u = x.u;
    u += 0x7fffu + ((u >> 16) & 1u);   // round-to-nearest-even
    return (unsigned short)(u >> 16);
}

// ---------------------------------------- features fp32 -> bf16 (gather diet)
__global__ __launch_bounds__(256) void k_feat(const float* __restrict__ f,
                                              unsigned short* __restrict__ f2) {
    const unsigned i = (blockIdx.x * 256u + threadIdx.x) * 4u;
    if (i < (unsigned)(NN * IND)) {
        const float4 v = *(const float4*)(f + i);
        ushort4 o;
        o.x = f2bf(v.x); o.y = f2bf(v.y); o.z = f2bf(v.z); o.w = f2bf(v.w);
        *(ushort4*)(f2 + i) = o;
    }
}

// ---------------- Wt[r][o][k] bf16, K zero-padded (+ folds hist zeroing in)
__global__ __launch_bounds__(256) void k_wt(const float* __restrict__ comps,
                                            const float* __restrict__ bases,
                                            unsigned short* __restrict__ wt,
                                            unsigned* __restrict__ hist) {
    const unsigned idx = blockIdx.x * 256u + threadIdx.x;   // exactly 856064
    if (idx < RN) hist[idx] = 0u;                            // zero histogram
    const unsigned r   = idx / (OUTD * KP);
    const unsigned rem = idx - r * (OUTD * KP);
    const unsigned o   = rem / KP;
    const unsigned k   = rem - o * KP;
    float acc = 0.f;
    if (k < IND) {
#pragma unroll
        for (int b = 0; b < BB; ++b)
            acc += comps[r * BB + b] * bases[((unsigned)b * IND + k) * OUTD + o];
    }
    wt[idx] = f2bf(acc);
}

// ---------------------------------------------------------------- histogram
__global__ __launch_bounds__(256) void k_hist(const int* __restrict__ esrc,
                                              const int* __restrict__ erel,
                                              unsigned* __restrict__ hist) {
    const int e = blockIdx.x * 256 + threadIdx.x;           // exactly 640000
    const unsigned key = (unsigned)erel[e] * NN + (unsigned)esrc[e];
    atomicAdd(&hist[key], 1u);
}

// ------------------------------------------------- scan level 1 (1024/block)
__global__ __launch_bounds__(256) void k_scan1(const unsigned* __restrict__ hist,
                                               unsigned* __restrict__ off,
                                               unsigned* __restrict__ bsum) {
    __shared__ unsigned sc[256];
    const int tid = threadIdx.x;
    const unsigned base = blockIdx.x * 1024u + (unsigned)tid * 4u;
    unsigned v0 = (base + 0 < RN) ? hist[base + 0] : 0u;
    unsigned v1 = (base + 1 < RN) ? hist[base + 1] : 0u;
    unsigned v2 = (base + 2 < RN) ? hist[base + 2] : 0u;
    unsigned v3 = (base + 3 < RN) ? hist[base + 3] : 0u;
    const unsigned s = v0 + v1 + v2 + v3;
    sc[tid] = s;
    __syncthreads();
    for (int d = 1; d < 256; d <<= 1) {
        unsigned t = (tid >= d) ? sc[tid - d] : 0u;
        __syncthreads();
        sc[tid] += t;
        __syncthreads();
    }
    if (tid == 255) bsum[blockIdx.x] = sc[255];
    unsigned run = sc[tid] - s;                              // exclusive
    if (base + 0 < RN) off[base + 0] = run; run += v0;
    if (base + 1 < RN) off[base + 1] = run; run += v1;
    if (base + 2 < RN) off[base + 2] = run; run += v2;
    if (base + 3 < RN) off[base + 3] = run;
}

// ---------------------------- scan level 2: 64-lane shuffle scan (was serial)
__global__ __launch_bounds__(64) void k_scan2(unsigned* __restrict__ bsum) {
    const int lane = threadIdx.x;
    unsigned v[4];
    unsigned tot = 0;
#pragma unroll
    for (int i = 0; i < 4; ++i) {
        const int idx = lane * 4 + i;
        v[i] = (idx < NSCAN_BLOCKS) ? bsum[idx] : 0u;
        tot += v[i];
    }
    unsigned sc = tot;
    for (int d = 1; d < 64; d <<= 1) {
        unsigned t = __shfl_up(sc, d, 64);
        if (lane >= d) sc += t;
    }
    unsigned run = sc - tot;                                 // exclusive over lanes
#pragma unroll
    for (int i = 0; i < 4; ++i) {
        const int idx = lane * 4 + i;
        if (idx < NSCAN_BLOCKS) bsum[idx] = run;
        run += v[i];
    }
}

// ------------------------------------------------ scan level 3 (+cursor copy)
__global__ __launch_bounds__(256) void k_scan3(unsigned* __restrict__ off,
                                               unsigned* __restrict__ off2,
                                               const unsigned* __restrict__ bsum) {
    const unsigned idx = blockIdx.x * 256u + threadIdx.x;
    if (idx < RN) {
        const unsigned v = off[idx] + bsum[idx >> 10];
        off[idx]  = v;
        off2[idx] = v;
    }
    if (idx == 0) off[RN] = EE;
}

// ------------------------------------------------------- counting-sort scatter
__global__ __launch_bounds__(256) void k_scatter(const int* __restrict__ esrc,
                                                 const int* __restrict__ erel,
                                                 const int* __restrict__ edst,
                                                 unsigned* __restrict__ off2,
                                                 unsigned* __restrict__ ssd) {
    const int e = blockIdx.x * 256 + threadIdx.x;           // exactly 640000
    const unsigned src = (unsigned)esrc[e];
    const unsigned key = (unsigned)erel[e] * NN + src;
    const unsigned p = atomicAdd(&off2[key], 1u);
    ssd[p] = (src << 16) | (unsigned)edst[e];
}

// ---------------------------------------------------------------- fused main
// 32 nodes/block, 512 threads (8 waves). Per relation:
//   stage edge meta in LDS -> flat (edge x chunk) independent gather work-items
//   (high MLP, no per-wave dependent chains) -> scale+bf16 -> 19 MFMA k-steps.
// USE_BF16: gather from pre-converted bf16 features (half bytes, half iters);
// accumulator uses pair-split layout (even k in [0,150), odd k in [150,300))
// so both ds_add instructions stay conflict-free.
template<int USE_BF16>
__global__ __launch_bounds__(512) void k_main(const float* __restrict__ feat,
                                              const unsigned short* __restrict__ feat2,
                                              const float* __restrict__ bias,
                                              const unsigned* __restrict__ offs,
                                              const unsigned* __restrict__ ssd,
                                              const unsigned short* __restrict__ wt,
                                              float* __restrict__ out) {
    __shared__ float s32[32 * IND];
    __shared__ __align__(16) unsigned short sbf[32 * SBS];
    __shared__ unsigned sme[CHUNK];

    const int tid  = threadIdx.x;
    const int wave = tid >> 6;
    const int lane = tid & 63;
    const int row  = lane & 31;      // MFMA: A row / B col / C col
    const int q    = lane >> 5;
    const int n0   = blockIdx.x * 32;
    const int o0   = wave * 32;      // each wave owns a 32-wide output stripe

    f32x16 acc;
#pragma unroll
    for (int i = 0; i < 16; ++i) acc[i] = 0.f;

    for (int r = 0; r < RR; ++r) {
        // --- zero fp32 accumulation tile
        for (int i = tid; i < 32 * IND; i += 512) s32[i] = 0.f;

        const unsigned e0 = offs[r * NN + n0];
        const unsigned e1 = offs[r * NN + n0 + 32];

        // --- chunked gather: stage meta, then flat independent work-items
        for (unsigned base = e0; base < e1; base += CHUNK) {
            const unsigned nE = min((unsigned)CHUNK, e1 - base);
            for (unsigned j = (unsigned)tid; j < nE; j += 512u)
                sme[j] = ssd[base + j];
            __syncthreads();

            if (USE_BF16) {
                // unit = 1 uint = 2 bf16; 150 units/row, padded to 160
                const unsigned nW = nE * 160u;
                for (unsigned idx = (unsigned)tid; idx < nW; idx += 512u) {
                    const unsigned e  = ((idx >> 5) * 52429u) >> 18;   // /160
                    const unsigned k2 = idx - e * 160u;
                    if (k2 < 150u) {
                        const unsigned sd = sme[e];
                        const int m       = (int)(sd >> 16) - n0;
                        const unsigned d  = sd & 0xFFFFu;
                        const unsigned pv =
                            ((const unsigned*)(feat2 + (size_t)d * IND))[k2];
                        float* sp = s32 + m * IND;
                        atomicAdd(sp + k2,       __uint_as_float(pv << 16));
                        atomicAdd(sp + 150 + k2, __uint_as_float(pv & 0xFFFF0000u));
                    }
                }
            } else {
                // unit = 1 float; 300 units/row, padded to 320
                const unsigned nW = nE * 320u;
                for (unsigned idx = (unsigned)tid; idx < nW; idx += 512u) {
                    const unsigned e = ((idx >> 6) * 52429u) >> 18;    // /320
                    const unsigned k = idx - e * 320u;
                    if (k < (unsigned)IND) {
                        const unsigned sd = sme[e];
                        const int m       = (int)(sd >> 16) - n0;
                        const unsigned d  = sd & 0xFFFFu;
                        const float v     = feat[(size_t)d * IND + k];
                        atomicAdd(s32 + m * IND + k, v);
                    }
                }
            }
            __syncthreads();
        }

        // --- scale by 1/deg and convert to bf16 (zero-pad K to 304, pad to 308)
        {
            const int m  = tid >> 4;
            const int k0 = tid & 15;
            const unsigned c0 = offs[r * NN + n0 + m];
            const unsigned c1 = offs[r * NN + n0 + m + 1];
            const float inv = (c1 > c0) ? 1.0f / (float)(c1 - c0) : 0.f;
            for (int k = k0; k < SBS; k += 16) {
                float v = 0.f;
                if (k < IND) {
                    const int slot = USE_BF16 ? ((k & 1) ? 150 + (k >> 1) : (k >> 1))
                                              : k;
                    v = s32[m * IND + slot] * inv;
                }
                sbf[m * SBS + k] = f2bf(v);
            }
        }
        __syncthreads();

        // --- MFMA: C[32 nodes x 32 outs] += A[32 x 304] * B[304 x 32]
        const unsigned short* wb = wt + ((size_t)(r * OUTD + o0 + row) * KP) + 8 * q;
        const unsigned short* ab = sbf + row * SBS + 8 * q;
#pragma unroll
        for (int ks = 0; ks < 19; ++ks) {
            const int kk = ks * 16;
            U8 a, b;
            a.h[0] = *(const ushort4*)(ab + kk);
            a.h[1] = *(const ushort4*)(ab + kk + 4);
            b.q    = *(const uint4*)(wb + kk);
            acc = __builtin_amdgcn_mfma_f32_32x32x16_bf16(a.v, b.v, acc, 0, 0, 0);
        }
        // safe: next writes to s32/sme/sbf are each behind >=1 barrier from here
    }

    // --- epilogue: C/D layout col=lane&31, row=(reg&3)+8*(reg>>2)+4*(lane>>5)
    const int o = o0 + row;
    const float bv = bias[o];
#pragma unroll
    for (int reg = 0; reg < 16; ++reg) {
        const int node = (reg & 3) + 8 * (reg >> 2) + 4 * q;
        out[(size_t)(n0 + node) * OUTD + o] = acc[reg] + bv;
    }
}

extern "C" void kernel_launch(void* const* d_in, const int* in_sizes, int n_in,
                              void* d_out, int out_size, void* d_ws, size_t ws_size,
                              hipStream_t stream) {
    const float* feat  = (const float*)d_in[0];
    const float* comps = (const float*)d_in[1];
    const float* bases = (const float*)d_in[2];
    const float* bias  = (const float*)d_in[3];
    const int*   esrc  = (const int*)d_in[4];
    const int*   erel  = (const int*)d_in[5];
    const int*   edst  = (const int*)d_in[6];
    float* out = (float*)d_out;

    char* ws = (char*)d_ws;
    // ws layout (bytes):
    unsigned short* wt    = (unsigned short*)(ws + 0);        // 1,712,128
    unsigned*       hist  = (unsigned*)(ws + 1712128);        // 880,000
    unsigned*       off   = (unsigned*)(ws + 2592128);        // 880,004 (+pad)
    unsigned*       off2  = (unsigned*)(ws + 3472144);        // 880,000
    unsigned*       bsum  = (unsigned*)(ws + 4352144);        // 860 (+pad)
    unsigned*       ssd   = (unsigned*)(ws + 4353024);        // 2,560,000
    unsigned short* feat2 = (unsigned short*)(ws + 6913024);  // 12,000,000 -> 18,913,024

    // host-uniform (same every call): bf16 feature path only if scratch fits
    const bool use_bf16 = ws_size >= (size_t)18913024;

    if (use_bf16)
        hipLaunchKernelGGL(k_feat, dim3(5860), dim3(256), 0, stream, feat, feat2);
    hipLaunchKernelGGL(k_wt,      dim3(3344), dim3(256), 0, stream, comps, bases, wt, hist);
    hipLaunchKernelGGL(k_hist,    dim3(2500), dim3(256), 0, stream, esrc, erel, hist);
    hipLaunchKernelGGL(k_scan1,   dim3(NSCAN_BLOCKS), dim3(256), 0, stream, hist, off, bsum);
    hipLaunchKernelGGL(k_scan2,   dim3(1),    dim3(64),  0, stream, bsum);
    hipLaunchKernelGGL(k_scan3,   dim3(860),  dim3(256), 0, stream, off, off2, bsum);
    hipLaunchKernelGGL(k_scatter, dim3(2500), dim3(256), 0, stream, esrc, erel, edst, off2, ssd);
    if (use_bf16)
        hipLaunchKernelGGL((k_main<1>), dim3(625), dim3(512), 0, stream,
                           feat, feat2, bias, off, ssd, wt, out);
    else
        hipLaunchKernelGGL((k_main<0>), dim3(625), dim3(512), 0, stream,
                           feat, feat2, bias, off, ssd, wt, out);

    (void)in_sizes; (void)n_in; (void)out_size; (void)ws_size;
}

// Round 3
// 355.298 us; speedup vs baseline: 4.2451x; 4.2365x over previous
//
#include <hip/hip_runtime.h>

// Problem constants (fixed by reference)
#define NN   20000
#define RR   11
#define BB   8
#define IND  300
#define OUTD 256
#define EE   640000
#define RN   (RR * NN)      // 220000 buckets, key = rel*N + src
#define KP   304            // K padded to 19 * 16 for 32x32x16 MFMA
#define SBS  308            // LDS bf16 row stride (616B; 2-way bank aliasing = free)
#define NSCAN_BLOCKS 215    // ceil(220000 / 1024)
#define SME  768            // staged edges per (block, relation); mean ~93, P(>768)~0
#define FEATB 5860          // blocks converting features (5860*1024 >= 6,000,000)
#define WTB   3344          // blocks building wt (3344*256 == 11*256*304)

typedef short bf16x8 __attribute__((ext_vector_type(8)));
typedef float f32x16 __attribute__((ext_vector_type(16)));

union U8 {
    bf16x8  v;
    ushort4 h[2];
    uint4   q;
};

__device__ inline unsigned short f2bf(float f) {
    union { float f; unsigned u; } x;
    x.f = f;
    unsigned u = x.u;
    u += 0x7fffu + ((u >> 16) & 1u);   // round-to-nearest-even
    return (unsigned short)(u >> 16);
}
__device__ inline float bflo(unsigned p) { return __uint_as_float(p << 16); }
__device__ inline float bfhi(unsigned p) { return __uint_as_float(p & 0xFFFF0000u); }
__device__ inline unsigned packbf(float x, float y) {
    return (unsigned)f2bf(x) | ((unsigned)f2bf(y) << 16);
}

// -------- fused prep: feat fp32->bf16, Wt[r][o][k] bf16 build, hist zeroing
__global__ __launch_bounds__(256) void k_prep(const float* __restrict__ feat,
                                              const float* __restrict__ comps,
                                              const float* __restrict__ bases,
                                              unsigned short* __restrict__ f2,
                                              unsigned short* __restrict__ wt,
                                              unsigned* __restrict__ hist,
                                              int feat_blocks) {
    const unsigned b = blockIdx.x;
    if ((int)b < feat_blocks) {
        const unsigned i = (b * 256u + threadIdx.x) * 4u;
        if (i < (unsigned)(NN * IND)) {
            const float4 v = *(const float4*)(feat + i);
            ushort4 o;
            o.x = f2bf(v.x); o.y = f2bf(v.y); o.z = f2bf(v.z); o.w = f2bf(v.w);
            *(ushort4*)(f2 + i) = o;
        }
        return;
    }
    const unsigned idx = (b - (unsigned)feat_blocks) * 256u + threadIdx.x;
    if (idx < RN) hist[idx] = 0u;                            // zero histogram
    const unsigned r   = idx / (OUTD * KP);
    const unsigned rem = idx - r * (OUTD * KP);
    const unsigned o   = rem / KP;
    const unsigned k   = rem - o * KP;
    float acc = 0.f;
    if (k < IND) {
#pragma unroll
        for (int bb = 0; bb < BB; ++bb)
            acc += comps[r * BB + bb] * bases[((unsigned)bb * IND + k) * OUTD + o];
    }
    wt[idx] = f2bf(acc);
}

// ---------------------------------------------------------------- histogram
__global__ __launch_bounds__(256) void k_hist(const int* __restrict__ esrc,
                                              const int* __restrict__ erel,
                                              unsigned* __restrict__ hist) {
    const int e = blockIdx.x * 256 + threadIdx.x;           // exactly 640000
    const unsigned key = (unsigned)erel[e] * NN + (unsigned)esrc[e];
    atomicAdd(&hist[key], 1u);
}

// ------------------------------------------------- scan level 1 (1024/block)
__global__ __launch_bounds__(256) void k_scan1(const unsigned* __restrict__ hist,
                                               unsigned* __restrict__ off,
                                               unsigned* __restrict__ bsum) {
    __shared__ unsigned sc[256];
    const int tid = threadIdx.x;
    const unsigned base = blockIdx.x * 1024u + (unsigned)tid * 4u;
    unsigned v0 = (base + 0 < RN) ? hist[base + 0] : 0u;
    unsigned v1 = (base + 1 < RN) ? hist[base + 1] : 0u;
    unsigned v2 = (base + 2 < RN) ? hist[base + 2] : 0u;
    unsigned v3 = (base + 3 < RN) ? hist[base + 3] : 0u;
    const unsigned s = v0 + v1 + v2 + v3;
    sc[tid] = s;
    __syncthreads();
    for (int d = 1; d < 256; d <<= 1) {
        unsigned t = (tid >= d) ? sc[tid - d] : 0u;
        __syncthreads();
        sc[tid] += t;
        __syncthreads();
    }
    if (tid == 255) bsum[blockIdx.x] = sc[255];
    unsigned run = sc[tid] - s;                              // exclusive
    if (base + 0 < RN) off[base + 0] = run; run += v0;
    if (base + 1 < RN) off[base + 1] = run; run += v1;
    if (base + 2 < RN) off[base + 2] = run; run += v2;
    if (base + 3 < RN) off[base + 3] = run;
}

// ---------------------------- scan level 2: 64-lane shuffle scan
__global__ __launch_bounds__(64) void k_scan2(unsigned* __restrict__ bsum) {
    const int lane = threadIdx.x;
    unsigned v[4];
    unsigned tot = 0;
#pragma unroll
    for (int i = 0; i < 4; ++i) {
        const int idx = lane * 4 + i;
        v[i] = (idx < NSCAN_BLOCKS) ? bsum[idx] : 0u;
        tot += v[i];
    }
    unsigned sc = tot;
    for (int d = 1; d < 64; d <<= 1) {
        unsigned t = __shfl_up(sc, d, 64);
        if (lane >= d) sc += t;
    }
    unsigned run = sc - tot;                                 // exclusive over lanes
#pragma unroll
    for (int i = 0; i < 4; ++i) {
        const int idx = lane * 4 + i;
        if (idx < NSCAN_BLOCKS) bsum[idx] = run;
        run += v[i];
    }
}

// ------------------------------------------------ scan level 3 (+cursor copy)
__global__ __launch_bounds__(256) void k_scan3(unsigned* __restrict__ off,
                                               unsigned* __restrict__ off2,
                                               const unsigned* __restrict__ bsum) {
    const unsigned idx = blockIdx.x * 256u + threadIdx.x;
    if (idx < RN) {
        const unsigned v = off[idx] + bsum[idx >> 10];
        off[idx]  = v;
        off2[idx] = v;
    }
    if (idx == 0) off[RN] = EE;
}

// ------------------------------------------------------- counting-sort scatter
__global__ __launch_bounds__(256) void k_scatter(const int* __restrict__ esrc,
                                                 const int* __restrict__ erel,
                                                 const int* __restrict__ edst,
                                                 unsigned* __restrict__ off2,
                                                 unsigned* __restrict__ ssd) {
    const int e = blockIdx.x * 256 + threadIdx.x;           // exactly 640000
    const unsigned key = (unsigned)erel[e] * NN + (unsigned)esrc[e];
    const unsigned p = atomicAdd(&off2[key], 1u);
    ssd[p] = (unsigned)edst[e];                              // dst only; src = bucket
}

// ---------------------------------------------------------------- fused main
// 32 nodes/block, 512 threads (8 waves), ~24KB LDS -> 4 blocks/CU (wave cap).
// Owner-computes gather: wave w handles nodes 4w..4w+3; lanes = packed-bf16
// uint columns (3 slices of 64); per-edge coalesced loads accumulate in 6 fp32
// registers -> NO LDS atomics. Scale by 1/deg, pack, write MFMA A-tile, then
// 19 x v_mfma_f32_32x32x16_bf16 into persistent 32x32 acc per wave.
template<int USE_BF16>
__global__ __launch_bounds__(512, 8) void k_main(const float* __restrict__ feat,
                                                 const unsigned short* __restrict__ feat2,
                                                 const float* __restrict__ bias,
                                                 const unsigned* __restrict__ offs,
                                                 const unsigned* __restrict__ ssd,
                                                 const unsigned short* __restrict__ wt,
                                                 float* __restrict__ out) {
    __shared__ __align__(16) unsigned short sbf[32 * SBS];
    __shared__ unsigned sme[SME];
    __shared__ unsigned soffs[RR * 33];

    const int tid  = threadIdx.x;
    const int wave = tid >> 6;
    const int lane = tid & 63;
    const int row  = lane & 31;      // MFMA: A row / B col / C col
    const int q    = lane >> 5;
    const int n0   = blockIdx.x * 32;
    const int o0   = wave * 32;      // each wave owns a 32-wide output stripe

    // stage per-(rel,node) edge offsets; zero the K-pad uints (u=150..153) once
    if (tid < RR * 33) {
        const int r = tid / 33, j = tid - r * 33;
        soffs[tid] = offs[r * NN + n0 + j];
    }
    if (tid < 128)
        ((unsigned*)sbf)[(tid >> 2) * (SBS / 2) + 150 + (tid & 3)] = 0u;

    f32x16 acc;
#pragma unroll
    for (int i = 0; i < 16; ++i) acc[i] = 0.f;

    __syncthreads();

    for (int r = 0; r < RR; ++r) {
        const unsigned* so  = soffs + r * 33;
        const unsigned e0v  = so[0];
        const unsigned nE   = so[32] - e0v;
        for (unsigned j = (unsigned)tid; j < nE; j += 512u)
            sme[j] = ssd[e0v + j];
        __syncthreads();

#pragma unroll
        for (int g = 0; g < 4; ++g) {
            const int m = wave * 4 + g;
            const unsigned c0 = so[m], c1 = so[m + 1];
            if (USE_BF16) {
                float a0 = 0, a1 = 0, a2 = 0, a3 = 0, a4 = 0, a5 = 0;
                for (unsigned e = c0; e < c1; ++e) {
                    const unsigned d   = sme[e - e0v];
                    const unsigned* fp = (const unsigned*)feat2 + d * 150u;
                    const unsigned p0 = fp[lane];
                    const unsigned p1 = fp[lane + 64];
                    unsigned p2 = 0u;
                    if (lane < 22) p2 = fp[lane + 128];
                    a0 += bflo(p0); a1 += bfhi(p0);
                    a2 += bflo(p1); a3 += bfhi(p1);
                    a4 += bflo(p2); a5 += bfhi(p2);
                }
                const float inv = (c1 > c0) ? 1.0f / (float)(c1 - c0) : 0.f;
                unsigned* sp = (unsigned*)sbf + m * (SBS / 2);
                sp[lane]      = packbf(a0 * inv, a1 * inv);
                sp[lane + 64] = packbf(a2 * inv, a3 * inv);
                if (lane < 22) sp[lane + 128] = packbf(a4 * inv, a5 * inv);
            } else {
                float a0 = 0, a1 = 0, a2 = 0, a3 = 0, a4 = 0;
                for (unsigned e = c0; e < c1; ++e) {
                    const unsigned d = sme[e - e0v];
                    const float* fp  = feat + (size_t)d * IND;
                    a0 += fp[lane];
                    a1 += fp[lane + 64];
                    a2 += fp[lane + 128];
                    a3 += fp[lane + 192];
                    if (lane < 44) a4 += fp[lane + 256];
                }
                const float inv = (c1 > c0) ? 1.0f / (float)(c1 - c0) : 0.f;
                unsigned short* sp = sbf + m * SBS;
                sp[lane]       = f2bf(a0 * inv);
                sp[lane + 64]  = f2bf(a1 * inv);
                sp[lane + 128] = f2bf(a2 * inv);
                sp[lane + 192] = f2bf(a3 * inv);
                if (lane < 44) sp[lane + 256] = f2bf(a4 * inv);
            }
        }
        __syncthreads();

        // --- MFMA: C[32 nodes x 32 outs] += A[32 x 304] * B[304 x 32]
        const unsigned short* wb = wt + ((size_t)(r * OUTD + o0 + row) * KP) + 8 * q;
        const unsigned short* ab = sbf + row * SBS + 8 * q;
#pragma unroll
        for (int ks = 0; ks < 19; ++ks) {
            const int kk = ks * 16;
            U8 a, b;
            a.h[0] = *(const ushort4*)(ab + kk);
            a.h[1] = *(const ushort4*)(ab + kk + 4);
            b.q    = *(const uint4*)(wb + kk);
            acc = __builtin_amdgcn_mfma_f32_32x32x16_bf16(a.v, b.v, acc, 0, 0, 0);
        }
        // next sme/sbf writes are each behind >=1 barrier from these reads
    }

    // --- epilogue: C/D layout col=lane&31, row=(reg&3)+8*(reg>>2)+4*(lane>>5)
    const int o = o0 + row;
    const float bv = bias[o];
#pragma unroll
    for (int reg = 0; reg < 16; ++reg) {
        const int node = (reg & 3) + 8 * (reg >> 2) + 4 * q;
        out[(size_t)(n0 + node) * OUTD + o] = acc[reg] + bv;
    }
}

extern "C" void kernel_launch(void* const* d_in, const int* in_sizes, int n_in,
                              void* d_out, int out_size, void* d_ws, size_t ws_size,
                              hipStream_t stream) {
    const float* feat  = (const float*)d_in[0];
    const float* comps = (const float*)d_in[1];
    const float* bases = (const float*)d_in[2];
    const float* bias  = (const float*)d_in[3];
    const int*   esrc  = (const int*)d_in[4];
    const int*   erel  = (const int*)d_in[5];
    const int*   edst  = (const int*)d_in[6];
    float* out = (float*)d_out;

    char* ws = (char*)d_ws;
    // ws layout (bytes), 64-aligned segments:
    unsigned short* wt    = (unsigned short*)(ws + 0);        // 1,712,128
    unsigned*       hist  = (unsigned*)(ws + 1712128);        // 880,000
    unsigned*       off   = (unsigned*)(ws + 2592128);        // 880,064 (incl pad)
    unsigned*       off2  = (unsigned*)(ws + 3472192);        // 880,000
    unsigned*       bsum  = (unsigned*)(ws + 4352192);        // 1,024
    unsigned*       ssd   = (unsigned*)(ws + 4353216);        // 2,560,000
    unsigned short* feat2 = (unsigned short*)(ws + 6913216);  // 12,000,000 -> 18,913,216

    // host-uniform (same every call): bf16 feature path only if scratch fits
    const bool use_bf16 = ws_size >= (size_t)18913216;
    const int  featb    = use_bf16 ? FEATB : 0;

    hipLaunchKernelGGL(k_prep,    dim3(featb + WTB), dim3(256), 0, stream,
                       feat, comps, bases, feat2, wt, hist, featb);
    hipLaunchKernelGGL(k_hist,    dim3(2500), dim3(256), 0, stream, esrc, erel, hist);
    hipLaunchKernelGGL(k_scan1,   dim3(NSCAN_BLOCKS), dim3(256), 0, stream, hist, off, bsum);
    hipLaunchKernelGGL(k_scan2,   dim3(1),    dim3(64),  0, stream, bsum);
    hipLaunchKernelGGL(k_scan3,   dim3(860),  dim3(256), 0, stream, off, off2, bsum);
    hipLaunchKernelGGL(k_scatter, dim3(2500), dim3(256), 0, stream, esrc, erel, edst, off2, ssd);
    if (use_bf16)
        hipLaunchKernelGGL((k_main<1>), dim3(625), dim3(512), 0, stream,
                           feat, feat2, bias, off, ssd, wt, out);
    else
        hipLaunchKernelGGL((k_main<0>), dim3(625), dim3(512), 0, stream,
                           feat, feat2, bias, off, ssd, wt, out);

    (void)in_sizes; (void)n_in; (void)out_size; (void)ws_size;
}